// Round 1
// 371.829 us; speedup vs baseline: 1.0105x; 1.0105x over previous
//
#include <hip/hip_runtime.h>
#include <hip/hip_bf16.h>
#include <math.h>

#define B_TOT 262144

typedef __attribute__((ext_vector_type(8))) short v8s;
typedef __attribute__((ext_vector_type(4))) float v4f;

// ws layout (bf16 element offsets):
//  W1 frag-order   [0, 20480)        (8 n-tiles x 5 k-chunks x 512)
//  W2 frag-order   [20480, 36864)    (8 x 4 x 512)
//  Wf frag-order   [36864, 53248)    (8 x 4 x 512)
//  seen frag-order [53248, 67584)    (7 x 4 x 512, rows >=100 zero-padded)
//  s2 (fp32)       byte offset 135168, 112 floats (1e30 for pad rows)
#define WS_W1 0
#define WS_W2 20480
#define WS_WF 36864
#define WS_SEEN 53248
#define WS_S2_BYTES 135168

__device__ __forceinline__ unsigned short f2bf(float f) {
  union { float f; unsigned u; } cv; cv.f = f;
  unsigned u = cv.u;
  return (unsigned short)((u + 0x7FFFu + ((u >> 16) & 1u)) >> 16);  // RNE
}
__device__ __forceinline__ float bf2f(unsigned short h) {
  union { unsigned u; float f; } cv; cv.u = ((unsigned)h) << 16;
  return cv.f;
}
// packed RNE f32x2 -> bf16x2 (v_cvt_pk_bf16_f32 on gfx950); low 16 = x
__device__ __forceinline__ unsigned f2bf2(float x, float y) {
  float2 f; f.x = x; f.y = y;
  __hip_bfloat162 h = __float22bfloat162_rn(f);
  union { __hip_bfloat162 h; unsigned u; } cv; cv.h = h;
  return cv.u;
}

// Repack weights to bf16 in MFMA B-fragment-linear order.
// B-frag for (tile t, k-chunk c): lane L holds B[n = t*16 + (L&15)][k = c*32 + (L>>4)*8 + j]
__global__ void curiosity_prep(const float* __restrict__ W1, const float* __restrict__ W2,
                               const float* __restrict__ Wf, const float* __restrict__ seen,
                               unsigned short* __restrict__ wsb, float* __restrict__ s2) {
  int bid = blockIdx.x;
  if (bid < 264) {
    int idx = bid * 256 + (int)threadIdx.x;  // < 67584
    if (idx < 20480) {                       // W1: [128][160]
      int f = idx >> 9, r = idx & 511, L = r >> 3, j = r & 7;
      int t = f / 5, c = f - t * 5;
      int n = t * 16 + (L & 15), k = c * 32 + (L >> 4) * 8 + j;
      wsb[idx] = f2bf(W1[n * 160 + k]);
    } else if (idx < 36864) {                // W2: [128][128]
      int e = idx - 20480;
      int f = e >> 9, r = e & 511, L = r >> 3, j = r & 7;
      int t = f >> 2, c = f & 3;
      int n = t * 16 + (L & 15), k = c * 32 + (L >> 4) * 8 + j;
      wsb[idx] = f2bf(W2[n * 128 + k]);
    } else if (idx < 53248) {                // Wf: [128][128]
      int e = idx - 36864;
      int f = e >> 9, r = e & 511, L = r >> 3, j = r & 7;
      int t = f >> 2, c = f & 3;
      int n = t * 16 + (L & 15), k = c * 32 + (L >> 4) * 8 + j;
      wsb[idx] = f2bf(Wf[n * 128 + k]);
    } else {                                 // seen: [100->112][128]
      int e = idx - 53248;
      int f = e >> 9, r = e & 511, L = r >> 3, j = r & 7;
      int t = f >> 2, c = f & 3;
      int n = t * 16 + (L & 15), k = c * 32 + (L >> 4) * 8 + j;
      float v = (n < 100) ? seen[n * 128 + k] : 0.f;
      wsb[idx] = f2bf(v);
    }
  } else {                                   // s2: one wave per row
    int wv = (int)threadIdx.x >> 6, lane = (int)threadIdx.x & 63;
    int mm = (bid - 264) * 4 + wv;           // 0..111
    float s;
    if (mm < 100) {
      float v0 = seen[mm * 128 + lane], v1 = seen[mm * 128 + 64 + lane];
      s = v0 * v0 + v1 * v1;
#pragma unroll
      for (int msk = 1; msk < 64; msk <<= 1) s += __shfl_xor(s, msk, 64);
    } else {
      s = 1e30f;
    }
    if (lane == 0) s2[mm] = s;
  }
}

// pack two float4 (8 consecutive f32) into one bf16 A-fragment
__device__ __forceinline__ v8s cvt_frag(float4 lo, float4 hi) {
  union { v8s v; unsigned u[4]; } r;
  r.u[0] = f2bf2(lo.x, lo.y);
  r.u[1] = f2bf2(lo.z, lo.w);
  r.u[2] = f2bf2(hi.x, hi.y);
  r.u[3] = f2bf2(hi.z, hi.w);
  return r.v;
}

__device__ __forceinline__ v8s read_frag(const unsigned short* buf, int m, int q, int c) {
  return *(const v8s*)(buf + m * 136 + c * 32 + q * 8);
}
__device__ __forceinline__ v8s wfrag(const unsigned short* __restrict__ wsb,
                                     int base, int fragIdx, int lane) {
  return *(const v8s*)(wsb + base + fragIdx * 512 + lane * 8);
}

// 2048 blocks x 256 threads; 4 waves/block; each wave owns 32 rows (2 row-tiles
// sharing every B-fragment). A-fragments for state/action/next_state are loaded
// DIRECTLY from global into registers (the MFMA A layout is 8 consecutive k's of
// one row = two dwordx4) — no LDS staging round-trip for inputs. next_state is
// prefetched across GEMM2. GEMM3+GEMM4 share Wf fragments (fused per-tl).
// LDS only holds the h/pn/fa cross-lane shuffles. launch_bounds(256,3).
__global__ __launch_bounds__(256, 3) void curiosity_main(
    const float* __restrict__ state, const float* __restrict__ action,
    const float* __restrict__ next_state,
    const float* __restrict__ b1, const float* __restrict__ b2,
    const float* __restrict__ bfv,
    const unsigned short* __restrict__ wsb, const float* __restrict__ s2g,
    float* __restrict__ out) {
  __shared__ __attribute__((aligned(16))) unsigned short s_int[4][2][2176];
  __shared__ float s_o[3][128];

  const int tid = (int)threadIdx.x;
  const int w = tid >> 6, lane = tid & 63;
  const int m = lane & 15, q = lane >> 4;
  const int rowblk = (int)blockIdx.x * 128 + w * 32;

  unsigned short* buf[2] = { &s_int[w][0][0], &s_int[w][1][0] };

  // per-lane row pointers (lane L = row m of its tile, k-segment q*8)
  const float* st0 = state + (size_t)(rowblk + m) * 128 + q * 8;
  const float* st1 = st0 + 16 * 128;
  const float* ac0 = action + (size_t)(rowblk + m) * 32 + q * 8;
  const float* ac1 = ac0 + 16 * 32;
  const float* np0 = next_state + (size_t)(rowblk + m) * 128 + q * 8;
  const float* np1 = np0 + 16 * 128;

  // ---- GEMM1 A operands: 20 dwordx4 issued back-to-back (20 KB/wave in flight)
  float4 sv[2][4][2], av[2][2];
#pragma unroll
  for (int c = 0; c < 4; ++c) {
    sv[0][c][0] = *(const float4*)(st0 + c * 32);
    sv[0][c][1] = *(const float4*)(st0 + c * 32 + 4);
    sv[1][c][0] = *(const float4*)(st1 + c * 32);
    sv[1][c][1] = *(const float4*)(st1 + c * 32 + 4);
  }
  av[0][0] = *(const float4*)(ac0); av[0][1] = *(const float4*)(ac0 + 4);
  av[1][0] = *(const float4*)(ac1); av[1][1] = *(const float4*)(ac1 + 4);

  // biases (L2-resident, off critical path)
  float bv1[8], bv2[8], bvf[8];
#pragma unroll
  for (int tg = 0; tg < 8; ++tg) bv1[tg] = b1[tg * 16 + m];
#pragma unroll
  for (int tg = 0; tg < 8; ++tg) bv2[tg] = b2[tg * 16 + m];
#pragma unroll
  for (int tg = 0; tg < 8; ++tg) bvf[tg] = bfv[tg * 16 + m];

  v8s a1[2][5];
#pragma unroll
  for (int c = 0; c < 4; ++c) {
    a1[0][c] = cvt_frag(sv[0][c][0], sv[0][c][1]);
    a1[1][c] = cvt_frag(sv[1][c][0], sv[1][c][1]);
  }
  a1[0][4] = cvt_frag(av[0][0], av[0][1]);
  a1[1][4] = cvt_frag(av[1][0], av[1][1]);

  // ---- GEMM1: h = relu(x @ W1^T + b1) -> buf (bf16, cross-lane shuffle)
#pragma unroll
  for (int hf = 0; hf < 2; ++hf) {
    v8s bfr[20];
#pragma unroll
    for (int c = 0; c < 5; ++c)
#pragma unroll
      for (int tl = 0; tl < 4; ++tl)
        bfr[c * 4 + tl] = wfrag(wsb, WS_W1, (hf * 4 + tl) * 5 + c, lane);
    v4f acc[2][4] = {};
#pragma unroll
    for (int c = 0; c < 5; ++c)
#pragma unroll
      for (int tl = 0; tl < 4; ++tl) {
        acc[0][tl] = __builtin_amdgcn_mfma_f32_16x16x32_bf16(a1[0][c], bfr[c * 4 + tl], acc[0][tl], 0, 0, 0);
        acc[1][tl] = __builtin_amdgcn_mfma_f32_16x16x32_bf16(a1[1][c], bfr[c * 4 + tl], acc[1][tl], 0, 0, 0);
      }
#pragma unroll
    for (int tl = 0; tl < 4; ++tl) {
      int tg = hf * 4 + tl;
      float bv = bv1[tg];
#pragma unroll
      for (int tt = 0; tt < 2; ++tt)
#pragma unroll
        for (int r = 0; r < 4; r += 2) {
          unsigned p = f2bf2(fmaxf(acc[tt][tl][r] + bv, 0.f),
                             fmaxf(acc[tt][tl][r + 1] + bv, 0.f));
          buf[tt][(q * 4 + r) * 136 + tg * 16 + m] = (unsigned short)p;
          buf[tt][(q * 4 + r + 1) * 136 + tg * 16 + m] = (unsigned short)(p >> 16);
        }
    }
  }

  // ---- prefetch next_state tile 0 (8 dwordx4); tile 1 goes out mid-GEMM2
  float4 n0v[4][2], n1v[4][2];
#pragma unroll
  for (int c = 0; c < 4; ++c) {
    n0v[c][0] = *(const float4*)(np0 + c * 32);
    n0v[c][1] = *(const float4*)(np0 + c * 32 + 4);
  }

  // ---- GEMM2: pn = h @ W2^T + b2
  v8s af[2][4];
#pragma unroll
  for (int c = 0; c < 4; ++c) {
    af[0][c] = read_frag(buf[0], m, q, c);
    af[1][c] = read_frag(buf[1], m, q, c);
  }
  v8s a3[2][4];
#pragma unroll
  for (int hf = 0; hf < 2; ++hf) {
    if (hf == 1) {
      // tile0 loads have had GEMM2-hf0 to land: convert now, free payload,
      // and issue tile1 so it hides under GEMM2-hf1.
#pragma unroll
      for (int c = 0; c < 4; ++c) a3[0][c] = cvt_frag(n0v[c][0], n0v[c][1]);
#pragma unroll
      for (int c = 0; c < 4; ++c) {
        n1v[c][0] = *(const float4*)(np1 + c * 32);
        n1v[c][1] = *(const float4*)(np1 + c * 32 + 4);
      }
    }
    v8s bfr[16];
#pragma unroll
    for (int c = 0; c < 4; ++c)
#pragma unroll
      for (int tl = 0; tl < 4; ++tl)
        bfr[c * 4 + tl] = wfrag(wsb, WS_W2, (hf * 4 + tl) * 4 + c, lane);
    v4f acc[2][4] = {};
#pragma unroll
    for (int c = 0; c < 4; ++c)
#pragma unroll
      for (int tl = 0; tl < 4; ++tl) {
        acc[0][tl] = __builtin_amdgcn_mfma_f32_16x16x32_bf16(af[0][c], bfr[c * 4 + tl], acc[0][tl], 0, 0, 0);
        acc[1][tl] = __builtin_amdgcn_mfma_f32_16x16x32_bf16(af[1][c], bfr[c * 4 + tl], acc[1][tl], 0, 0, 0);
      }
#pragma unroll
    for (int tl = 0; tl < 4; ++tl) {
      int tg = hf * 4 + tl;
      float bv = bv2[tg];
#pragma unroll
      for (int tt = 0; tt < 2; ++tt)
#pragma unroll
        for (int r = 0; r < 4; r += 2) {
          unsigned p = f2bf2(acc[tt][tl][r] + bv, acc[tt][tl][r + 1] + bv);
          buf[tt][(q * 4 + r) * 136 + tg * 16 + m] = (unsigned short)p;
          buf[tt][(q * 4 + r + 1) * 136 + tg * 16 + m] = (unsigned short)(p >> 16);
        }
    }
  }

  // ---- pn A-frags from LDS, next_state tile1 frags from regs
  v8s a4[2][4];
#pragma unroll
  for (int c = 0; c < 4; ++c) {
    a4[0][c] = read_frag(buf[0], m, q, c);
    a4[1][c] = read_frag(buf[1], m, q, c);
  }
#pragma unroll
  for (int c = 0; c < 4; ++c) a3[1][c] = cvt_frag(n1v[c][0], n1v[c][1]);

  float s2v[7];
#pragma unroll
  for (int tl = 0; tl < 7; ++tl) s2v[tl] = s2g[tl * 16 + m];

  // ---- fused GEMM3+GEMM4: fa = relu(ns @ Wf^T + bf), fp = relu(pn @ Wf^T + bf)
  //      Wf B-frags loaded ONCE; pe += (fp-fa)^2, a2s += fa^2 in the epilogue;
  //      fa (bf16-rounded) -> buf for GEMM5's A-frags. acc held per-tl (16 regs).
  float pe[2][4] = {};
  float a2s[2][4] = {};
#pragma unroll
  for (int hf = 0; hf < 2; ++hf) {
#pragma unroll
    for (int tl = 0; tl < 4; ++tl) {
      v8s bfr[4];
#pragma unroll
      for (int c = 0; c < 4; ++c)
        bfr[c] = wfrag(wsb, WS_WF, (hf * 4 + tl) * 4 + c, lane);
      v4f fa0 = {}, fa1 = {}, fp0 = {}, fp1 = {};
#pragma unroll
      for (int c = 0; c < 4; ++c) {
        fa0 = __builtin_amdgcn_mfma_f32_16x16x32_bf16(a3[0][c], bfr[c], fa0, 0, 0, 0);
        fa1 = __builtin_amdgcn_mfma_f32_16x16x32_bf16(a3[1][c], bfr[c], fa1, 0, 0, 0);
        fp0 = __builtin_amdgcn_mfma_f32_16x16x32_bf16(a4[0][c], bfr[c], fp0, 0, 0, 0);
        fp1 = __builtin_amdgcn_mfma_f32_16x16x32_bf16(a4[1][c], bfr[c], fp1, 0, 0, 0);
      }
      int tg = hf * 4 + tl;
      float bv = bvf[tg];
#pragma unroll
      for (int tt = 0; tt < 2; ++tt) {
        const v4f& fav = tt ? fa1 : fa0;
        const v4f& fpv = tt ? fp1 : fp0;
#pragma unroll
        for (int rp = 0; rp < 2; ++rp) {
          int r = rp * 2;
          unsigned p = f2bf2(fmaxf(fav[r] + bv, 0.f),
                             fmaxf(fav[r + 1] + bv, 0.f));
          buf[tt][(q * 4 + r) * 136 + tg * 16 + m] = (unsigned short)p;
          buf[tt][(q * 4 + r + 1) * 136 + tg * 16 + m] = (unsigned short)(p >> 16);
          float flo = bf2f((unsigned short)p), fhi = bf2f((unsigned short)(p >> 16));
          a2s[tt][r] += flo * flo;
          a2s[tt][r + 1] += fhi * fhi;
          float d0 = fmaxf(fpv[r] + bv, 0.f) - flo;
          float d1 = fmaxf(fpv[r + 1] + bv, 0.f) - fhi;
          pe[tt][r] += d0 * d0;
          pe[tt][r + 1] += d1 * d1;
        }
      }
    }
  }

  // reduce pe / ||fa||^2 across the 16 lanes of each quad
#pragma unroll
  for (int tt = 0; tt < 2; ++tt)
#pragma unroll
    for (int r = 0; r < 4; ++r)
#pragma unroll
      for (int msk = 1; msk < 16; msk <<= 1) {
        pe[tt][r] += __shfl_xor(pe[tt][r], msk, 16);
        a2s[tt][r] += __shfl_xor(a2s[tt][r], msk, 16);
      }

  // ---- GEMM5: g = fa @ seen^T (N=112 incl pad), d2 = a2 + s2 - 2g
  v8s a5[2][4];
#pragma unroll
  for (int c = 0; c < 4; ++c) {
    a5[0][c] = read_frag(buf[0], m, q, c);
    a5[1][c] = read_frag(buf[1], m, q, c);
  }
  float dmin[2][4] = {{3.4e38f, 3.4e38f, 3.4e38f, 3.4e38f},
                      {3.4e38f, 3.4e38f, 3.4e38f, 3.4e38f}};
  {
    v8s bfr[16];
#pragma unroll
    for (int tl = 0; tl < 4; ++tl)
#pragma unroll
      for (int c = 0; c < 4; ++c)
        bfr[tl * 4 + c] = wfrag(wsb, WS_SEEN, tl * 4 + c, lane);
#pragma unroll
    for (int tl = 0; tl < 4; ++tl) {
      v4f g0 = {}, g1 = {};
#pragma unroll
      for (int c = 0; c < 4; ++c) {
        g0 = __builtin_amdgcn_mfma_f32_16x16x32_bf16(a5[0][c], bfr[tl * 4 + c], g0, 0, 0, 0);
        g1 = __builtin_amdgcn_mfma_f32_16x16x32_bf16(a5[1][c], bfr[tl * 4 + c], g1, 0, 0, 0);
      }
      float s2x = s2v[tl];
#pragma unroll
      for (int r = 0; r < 4; ++r) {
        dmin[0][r] = fminf(dmin[0][r], a2s[0][r] + s2x - 2.f * g0[r]);
        dmin[1][r] = fminf(dmin[1][r], a2s[1][r] + s2x - 2.f * g1[r]);
      }
    }
  }
  {
    v8s bfr[12];
#pragma unroll
    for (int tl = 0; tl < 3; ++tl)
#pragma unroll
      for (int c = 0; c < 4; ++c)
        bfr[tl * 4 + c] = wfrag(wsb, WS_SEEN, (tl + 4) * 4 + c, lane);
#pragma unroll
    for (int tl = 0; tl < 3; ++tl) {
      v4f g0 = {}, g1 = {};
#pragma unroll
      for (int c = 0; c < 4; ++c) {
        g0 = __builtin_amdgcn_mfma_f32_16x16x32_bf16(a5[0][c], bfr[tl * 4 + c], g0, 0, 0, 0);
        g1 = __builtin_amdgcn_mfma_f32_16x16x32_bf16(a5[1][c], bfr[tl * 4 + c], g1, 0, 0, 0);
      }
      float s2x = s2v[tl + 4];
#pragma unroll
      for (int r = 0; r < 4; ++r) {
        dmin[0][r] = fminf(dmin[0][r], a2s[0][r] + s2x - 2.f * g0[r]);
        dmin[1][r] = fminf(dmin[1][r], a2s[1][r] + s2x - 2.f * g1[r]);
      }
    }
  }
#pragma unroll
  for (int tt = 0; tt < 2; ++tt)
#pragma unroll
    for (int r = 0; r < 4; ++r)
#pragma unroll
      for (int msk = 1; msk < 16; msk <<= 1)
        dmin[tt][r] = fminf(dmin[tt][r], __shfl_xor(dmin[tt][r], msk, 16));

  if (m == 0) {
#pragma unroll
    for (int tt = 0; tt < 2; ++tt)
#pragma unroll
      for (int r = 0; r < 4; ++r) {
        int rl = w * 32 + tt * 16 + q * 4 + r;
        float p = pe[tt][r] * (1.f / 128.f);
        float nov = fminf(1.f, sqrtf(fmaxf(dmin[tt][r], 0.f)) * 0.1f);
        s_o[0][rl] = p;
        s_o[1][rl] = nov;
        s_o[2][rl] = 0.5f * (p + nov);
      }
  }
  __syncthreads();
  const size_t base = (size_t)blockIdx.x * 128;
  for (int idx = tid; idx < 384; idx += 256) {
    int j = idx >> 7, r = idx & 127;
    out[(size_t)j * B_TOT + base + r] = s_o[j][r];
  }
}

extern "C" void kernel_launch(void* const* d_in, const int* in_sizes, int n_in,
                              void* d_out, int out_size, void* d_ws, size_t ws_size,
                              hipStream_t stream) {
  const float* state      = (const float*)d_in[0];
  const float* action     = (const float*)d_in[1];
  const float* next_state = (const float*)d_in[2];
  const float* seen       = (const float*)d_in[3];
  const float* W1         = (const float*)d_in[4];
  const float* b1         = (const float*)d_in[5];
  const float* W2         = (const float*)d_in[6];
  const float* b2         = (const float*)d_in[7];
  const float* Wf         = (const float*)d_in[8];
  const float* bf_        = (const float*)d_in[9];

  unsigned short* wsb = (unsigned short*)d_ws;
  float* s2 = (float*)((char*)d_ws + WS_S2_BYTES);

  curiosity_prep<<<292, 256, 0, stream>>>(W1, W2, Wf, seen, wsb, s2);
  curiosity_main<<<2048, 256, 0, stream>>>(state, action, next_state, b1, b2, bf_,
                                           wsb, s2, (float*)d_out);
}

// Round 2
// 322.263 us; speedup vs baseline: 1.1659x; 1.1538x over previous
//
#include <hip/hip_runtime.h>
#include <hip/hip_bf16.h>
#include <math.h>

#define B_TOT 262144

typedef __attribute__((ext_vector_type(8))) short v8s;
typedef __attribute__((ext_vector_type(4))) float v4f;

// ws layout (bf16 element offsets):
//  W1 frag-order   [0, 20480)        (8 n-tiles x 5 k-chunks x 512)
//  W2 frag-order   [20480, 36864)    (8 x 4 x 512)
//  Wf frag-order   [36864, 53248)    (8 x 4 x 512)
//  seen frag-order [53248, 67584)    (7 x 4 x 512, rows >=100 zero-padded)
//  s2 (fp32)       byte offset 135168, 112 floats (1e30 for pad rows)
#define WS_W1 0
#define WS_W2 20480
#define WS_WF 36864
#define WS_SEEN 53248
#define WS_S2_BYTES 135168

__device__ __forceinline__ unsigned short f2bf(float f) {
  union { float f; unsigned u; } cv; cv.f = f;
  unsigned u = cv.u;
  return (unsigned short)((u + 0x7FFFu + ((u >> 16) & 1u)) >> 16);  // RNE
}
__device__ __forceinline__ float bf2f(unsigned short h) {
  union { unsigned u; float f; } cv; cv.u = ((unsigned)h) << 16;
  return cv.f;
}
// packed RNE f32x2 -> bf16x2 (v_cvt_pk_bf16_f32 on gfx950); low 16 = x
__device__ __forceinline__ unsigned f2bf2(float x, float y) {
  float2 f; f.x = x; f.y = y;
  __hip_bfloat162 h = __float22bfloat162_rn(f);
  union { __hip_bfloat162 h; unsigned u; } cv; cv.h = h;
  return cv.u;
}

// Repack weights to bf16 in MFMA B-fragment-linear order.
// B-frag for (tile t, k-chunk c): lane L holds B[n = t*16 + (L&15)][k = c*32 + (L>>4)*8 + j]
__global__ void curiosity_prep(const float* __restrict__ W1, const float* __restrict__ W2,
                               const float* __restrict__ Wf, const float* __restrict__ seen,
                               unsigned short* __restrict__ wsb, float* __restrict__ s2) {
  int bid = blockIdx.x;
  if (bid < 264) {
    int idx = bid * 256 + (int)threadIdx.x;  // < 67584
    if (idx < 20480) {                       // W1: [128][160]
      int f = idx >> 9, r = idx & 511, L = r >> 3, j = r & 7;
      int t = f / 5, c = f - t * 5;
      int n = t * 16 + (L & 15), k = c * 32 + (L >> 4) * 8 + j;
      wsb[idx] = f2bf(W1[n * 160 + k]);
    } else if (idx < 36864) {                // W2: [128][128]
      int e = idx - 20480;
      int f = e >> 9, r = e & 511, L = r >> 3, j = r & 7;
      int t = f >> 2, c = f & 3;
      int n = t * 16 + (L & 15), k = c * 32 + (L >> 4) * 8 + j;
      wsb[idx] = f2bf(W2[n * 128 + k]);
    } else if (idx < 53248) {                // Wf: [128][128]
      int e = idx - 36864;
      int f = e >> 9, r = e & 511, L = r >> 3, j = r & 7;
      int t = f >> 2, c = f & 3;
      int n = t * 16 + (L & 15), k = c * 32 + (L >> 4) * 8 + j;
      wsb[idx] = f2bf(Wf[n * 128 + k]);
    } else {                                 // seen: [100->112][128]
      int e = idx - 53248;
      int f = e >> 9, r = e & 511, L = r >> 3, j = r & 7;
      int t = f >> 2, c = f & 3;
      int n = t * 16 + (L & 15), k = c * 32 + (L >> 4) * 8 + j;
      float v = (n < 100) ? seen[n * 128 + k] : 0.f;
      wsb[idx] = f2bf(v);
    }
  } else {                                   // s2: one wave per row
    int wv = (int)threadIdx.x >> 6, lane = (int)threadIdx.x & 63;
    int mm = (bid - 264) * 4 + wv;           // 0..111
    float s;
    if (mm < 100) {
      float v0 = seen[mm * 128 + lane], v1 = seen[mm * 128 + 64 + lane];
      s = v0 * v0 + v1 * v1;
#pragma unroll
      for (int msk = 1; msk < 64; msk <<= 1) s += __shfl_xor(s, msk, 64);
    } else {
      s = 1e30f;
    }
    if (lane == 0) s2[mm] = s;
  }
}

// pack two float4 (8 consecutive f32) into one bf16 A-fragment
__device__ __forceinline__ v8s cvt_frag(float4 lo, float4 hi) {
  union { v8s v; unsigned u[4]; } r;
  r.u[0] = f2bf2(lo.x, lo.y);
  r.u[1] = f2bf2(lo.z, lo.w);
  r.u[2] = f2bf2(hi.x, hi.y);
  r.u[3] = f2bf2(hi.z, hi.w);
  return r.v;
}

__device__ __forceinline__ v8s read_frag(const unsigned short* buf, int m, int q, int c) {
  return *(const v8s*)(buf + m * 136 + c * 32 + q * 8);
}

// async global->LDS, 16B per lane; dest is wave-uniform base + lane*16 (linear),
// source is per-lane. wsb frag-linear layout == the identity map, so read offsets
// (frag*512 + lane*8 shorts) match staged offsets exactly.
__device__ __forceinline__ void gload_lds16(const unsigned short* g, unsigned short* l) {
  __builtin_amdgcn_global_load_lds(
      (const __attribute__((address_space(1))) unsigned int*)g,
      (__attribute__((address_space(3))) unsigned int*)l, 16, 0, 0);
}
template <int N>
__device__ __forceinline__ void stage_frags(const unsigned short* __restrict__ g,
                                            unsigned short* l, int f0, int lane) {
#pragma unroll
  for (int i = 0; i < N; ++i)
    gload_lds16(g + (size_t)(f0 + i) * 512 + lane * 8, l + (size_t)(f0 + i) * 512);
}
__device__ __forceinline__ v8s sfrag(const unsigned short* s_wt, int frag, int lane) {
  return *(const v8s*)(s_wt + frag * 512 + lane * 8);
}

// 2048 blocks x 256 threads; 4 waves/block; each wave owns 32 rows (2 row-tiles).
// Weights staged per-BLOCK into LDS (global_load_lds, frag-linear) one phase at a
// time behind a double-barrier protocol; waves read B-frags via ds_read_b128.
// Inputs loaded direct-to-reg in fully batched bursts (256-VGPR budget at
// launch_bounds(256,2) so the compiler does not serialize the batches).
// LDS: 32KB stage + 34KB tiles + 1.5KB out = 67.5KB -> 2 blocks/CU.
__global__ __launch_bounds__(256, 2) void curiosity_main(
    const float* __restrict__ state, const float* __restrict__ action,
    const float* __restrict__ next_state,
    const float* __restrict__ b1, const float* __restrict__ b2,
    const float* __restrict__ bfv,
    const unsigned short* __restrict__ wsb, const float* __restrict__ s2g,
    float* __restrict__ out) {
  __shared__ __attribute__((aligned(16))) unsigned short s_wt[16384];   // 32 KB stage
  __shared__ __attribute__((aligned(16))) unsigned short s_int[4][2][2176];
  __shared__ float s_o[3][128];

  const int tid = (int)threadIdx.x;
  const int w = tid >> 6, lane = tid & 63;
  const int m = lane & 15, q = lane >> 4;
  const int rowblk = (int)blockIdx.x * 128 + w * 32;

  unsigned short* buf[2] = { &s_int[w][0][0], &s_int[w][1][0] };

  // per-lane row pointers (lane L = row m of its tile, k-segment q*8)
  const float* st0 = state + (size_t)(rowblk + m) * 128 + q * 8;
  const float* st1 = st0 + 16 * 128;
  const float* ac0 = action + (size_t)(rowblk + m) * 32 + q * 8;
  const float* ac1 = ac0 + 16 * 32;
  const float* np0 = next_state + (size_t)(rowblk + m) * 128 + q * 8;
  const float* np1 = np0 + 16 * 128;

  // ---- input burst: 20 dwordx4 batched (no serialization at 256-VGPR budget)
  float4 sv[2][4][2], av[2][2];
#pragma unroll
  for (int c = 0; c < 4; ++c) {
    sv[0][c][0] = *(const float4*)(st0 + c * 32);
    sv[0][c][1] = *(const float4*)(st0 + c * 32 + 4);
    sv[1][c][0] = *(const float4*)(st1 + c * 32);
    sv[1][c][1] = *(const float4*)(st1 + c * 32 + 4);
  }
  av[0][0] = *(const float4*)(ac0); av[0][1] = *(const float4*)(ac0 + 4);
  av[1][0] = *(const float4*)(ac1); av[1][1] = *(const float4*)(ac1 + 4);

  float bv1[8];
#pragma unroll
  for (int tg = 0; tg < 8; ++tg) bv1[tg] = b1[tg * 16 + m];

  // ---- stage W1 hf0 (frags 0..19, 5 per wave), then one barrier covers
  //      both the stage and the input burst drain.
  stage_frags<5>(wsb + WS_W1, s_wt, w * 5, lane);
  __syncthreads();

  v8s a1[2][5];
#pragma unroll
  for (int c = 0; c < 4; ++c) {
    a1[0][c] = cvt_frag(sv[0][c][0], sv[0][c][1]);
    a1[1][c] = cvt_frag(sv[1][c][0], sv[1][c][1]);
  }
  a1[0][4] = cvt_frag(av[0][0], av[0][1]);
  a1[1][4] = cvt_frag(av[1][0], av[1][1]);

  // ---- GEMM1: h = relu(x @ W1^T + b1); two stage phases (W1 = 40KB)
#pragma unroll
  for (int hf = 0; hf < 2; ++hf) {
    if (hf == 1) {
      __syncthreads();                                   // hf0 frag reads done
      stage_frags<5>(wsb + WS_W1 + 20 * 512, s_wt, w * 5, lane);
      __syncthreads();                                   // hf1 staged
    }
    v8s bfr[20];
#pragma unroll
    for (int c = 0; c < 5; ++c)
#pragma unroll
      for (int tl = 0; tl < 4; ++tl)
        bfr[c * 4 + tl] = sfrag(s_wt, tl * 5 + c, lane);
    v4f acc[2][4] = {};
#pragma unroll
    for (int c = 0; c < 5; ++c)
#pragma unroll
      for (int tl = 0; tl < 4; ++tl) {
        acc[0][tl] = __builtin_amdgcn_mfma_f32_16x16x32_bf16(a1[0][c], bfr[c * 4 + tl], acc[0][tl], 0, 0, 0);
        acc[1][tl] = __builtin_amdgcn_mfma_f32_16x16x32_bf16(a1[1][c], bfr[c * 4 + tl], acc[1][tl], 0, 0, 0);
      }
#pragma unroll
    for (int tl = 0; tl < 4; ++tl) {
      int tg = hf * 4 + tl;
      float bv = bv1[tg];
#pragma unroll
      for (int tt = 0; tt < 2; ++tt)
#pragma unroll
        for (int r = 0; r < 4; r += 2) {
          unsigned p = f2bf2(fmaxf(acc[tt][tl][r] + bv, 0.f),
                             fmaxf(acc[tt][tl][r + 1] + bv, 0.f));
          buf[tt][(q * 4 + r) * 136 + tg * 16 + m] = (unsigned short)p;
          buf[tt][(q * 4 + r + 1) * 136 + tg * 16 + m] = (unsigned short)(p >> 16);
        }
    }
  }

  // ---- stage W2 whole (32 frags); slot af reads + bias loads under the barrier
  __syncthreads();
  stage_frags<8>(wsb + WS_W2, s_wt, w * 8, lane);
  float bv2[8];
#pragma unroll
  for (int tg = 0; tg < 8; ++tg) bv2[tg] = b2[tg * 16 + m];
  v8s af[2][4];
#pragma unroll
  for (int c = 0; c < 4; ++c) {
    af[0][c] = read_frag(buf[0], m, q, c);
    af[1][c] = read_frag(buf[1], m, q, c);
  }
  __syncthreads();

  // ---- next_state burst issued here; drains at the Wf-phase barrier (hidden
  //      under GEMM2's compute).
  float4 n0v[4][2], n1v[4][2];
#pragma unroll
  for (int c = 0; c < 4; ++c) {
    n0v[c][0] = *(const float4*)(np0 + c * 32);
    n0v[c][1] = *(const float4*)(np0 + c * 32 + 4);
    n1v[c][0] = *(const float4*)(np1 + c * 32);
    n1v[c][1] = *(const float4*)(np1 + c * 32 + 4);
  }

  // ---- GEMM2: pn = h @ W2^T + b2
#pragma unroll
  for (int hf = 0; hf < 2; ++hf) {
    v8s bfr[16];
#pragma unroll
    for (int c = 0; c < 4; ++c)
#pragma unroll
      for (int tl = 0; tl < 4; ++tl)
        bfr[c * 4 + tl] = sfrag(s_wt, (hf * 4 + tl) * 4 + c, lane);
    v4f acc[2][4] = {};
#pragma unroll
    for (int c = 0; c < 4; ++c)
#pragma unroll
      for (int tl = 0; tl < 4; ++tl) {
        acc[0][tl] = __builtin_amdgcn_mfma_f32_16x16x32_bf16(af[0][c], bfr[c * 4 + tl], acc[0][tl], 0, 0, 0);
        acc[1][tl] = __builtin_amdgcn_mfma_f32_16x16x32_bf16(af[1][c], bfr[c * 4 + tl], acc[1][tl], 0, 0, 0);
      }
#pragma unroll
    for (int tl = 0; tl < 4; ++tl) {
      int tg = hf * 4 + tl;
      float bv = bv2[tg];
#pragma unroll
      for (int tt = 0; tt < 2; ++tt)
#pragma unroll
        for (int r = 0; r < 4; r += 2) {
          unsigned p = f2bf2(acc[tt][tl][r] + bv, acc[tt][tl][r + 1] + bv);
          buf[tt][(q * 4 + r) * 136 + tg * 16 + m] = (unsigned short)p;
          buf[tt][(q * 4 + r + 1) * 136 + tg * 16 + m] = (unsigned short)(p >> 16);
        }
    }
  }

  // ---- stage Wf whole; slot a4 (pn) reads + bias under barrier
  __syncthreads();
  stage_frags<8>(wsb + WS_WF, s_wt, w * 8, lane);
  float bvf[8];
#pragma unroll
  for (int tg = 0; tg < 8; ++tg) bvf[tg] = bfv[tg * 16 + m];
  v8s a4[2][4];
#pragma unroll
  for (int c = 0; c < 4; ++c) {
    a4[0][c] = read_frag(buf[0], m, q, c);
    a4[1][c] = read_frag(buf[1], m, q, c);
  }
  __syncthreads();   // also drains the next_state burst

  v8s a3[2][4];
#pragma unroll
  for (int c = 0; c < 4; ++c) {
    a3[0][c] = cvt_frag(n0v[c][0], n0v[c][1]);
    a3[1][c] = cvt_frag(n1v[c][0], n1v[c][1]);
  }

  // ---- fused GEMM3+GEMM4: fa = relu(ns @ Wf^T + bf), fp = relu(pn @ Wf^T + bf)
  //      Wf B-frags read ONCE from LDS; pe += (fp-fa)^2, a2s += fa^2 in epilogue;
  //      fa (bf16-rounded) -> buf for GEMM5's A-frags.
  float pe[2][4] = {};
  float a2s[2][4] = {};
#pragma unroll
  for (int hf = 0; hf < 2; ++hf) {
    v8s bfr[16];
#pragma unroll
    for (int tl = 0; tl < 4; ++tl)
#pragma unroll
      for (int c = 0; c < 4; ++c)
        bfr[tl * 4 + c] = sfrag(s_wt, (hf * 4 + tl) * 4 + c, lane);
#pragma unroll
    for (int tl = 0; tl < 4; ++tl) {
      v4f fa0 = {}, fa1 = {}, fp0 = {}, fp1 = {};
#pragma unroll
      for (int c = 0; c < 4; ++c) {
        fa0 = __builtin_amdgcn_mfma_f32_16x16x32_bf16(a3[0][c], bfr[tl * 4 + c], fa0, 0, 0, 0);
        fa1 = __builtin_amdgcn_mfma_f32_16x16x32_bf16(a3[1][c], bfr[tl * 4 + c], fa1, 0, 0, 0);
        fp0 = __builtin_amdgcn_mfma_f32_16x16x32_bf16(a4[0][c], bfr[tl * 4 + c], fp0, 0, 0, 0);
        fp1 = __builtin_amdgcn_mfma_f32_16x16x32_bf16(a4[1][c], bfr[tl * 4 + c], fp1, 0, 0, 0);
      }
      int tg = hf * 4 + tl;
      float bv = bvf[tg];
#pragma unroll
      for (int tt = 0; tt < 2; ++tt) {
        const v4f& fav = tt ? fa1 : fa0;
        const v4f& fpv = tt ? fp1 : fp0;
#pragma unroll
        for (int rp = 0; rp < 2; ++rp) {
          int r = rp * 2;
          unsigned p = f2bf2(fmaxf(fav[r] + bv, 0.f),
                             fmaxf(fav[r + 1] + bv, 0.f));
          buf[tt][(q * 4 + r) * 136 + tg * 16 + m] = (unsigned short)p;
          buf[tt][(q * 4 + r + 1) * 136 + tg * 16 + m] = (unsigned short)(p >> 16);
          float flo = bf2f((unsigned short)p), fhi = bf2f((unsigned short)(p >> 16));
          a2s[tt][r] += flo * flo;
          a2s[tt][r + 1] += fhi * fhi;
          float d0 = fmaxf(fpv[r] + bv, 0.f) - flo;
          float d1 = fmaxf(fpv[r + 1] + bv, 0.f) - fhi;
          pe[tt][r] += d0 * d0;
          pe[tt][r + 1] += d1 * d1;
        }
      }
    }
  }

  // ---- stage seen; hide its latency under the pe/a2s shuffle reduce + a5 reads
  __syncthreads();
  stage_frags<7>(wsb + WS_SEEN, s_wt, w * 7, lane);
  float s2v[7];
#pragma unroll
  for (int tl = 0; tl < 7; ++tl) s2v[tl] = s2g[tl * 16 + m];
#pragma unroll
  for (int tt = 0; tt < 2; ++tt)
#pragma unroll
    for (int r = 0; r < 4; ++r)
#pragma unroll
      for (int msk = 1; msk < 16; msk <<= 1) {
        pe[tt][r] += __shfl_xor(pe[tt][r], msk, 16);
        a2s[tt][r] += __shfl_xor(a2s[tt][r], msk, 16);
      }
  v8s a5[2][4];
#pragma unroll
  for (int c = 0; c < 4; ++c) {
    a5[0][c] = read_frag(buf[0], m, q, c);
    a5[1][c] = read_frag(buf[1], m, q, c);
  }
  __syncthreads();

  // ---- GEMM5: g = fa @ seen^T (N=112 incl pad), d2 = a2 + s2 - 2g
  float dmin[2][4] = {{3.4e38f, 3.4e38f, 3.4e38f, 3.4e38f},
                      {3.4e38f, 3.4e38f, 3.4e38f, 3.4e38f}};
  {
    v8s bfr[16];
#pragma unroll
    for (int tl = 0; tl < 4; ++tl)
#pragma unroll
      for (int c = 0; c < 4; ++c)
        bfr[tl * 4 + c] = sfrag(s_wt, tl * 4 + c, lane);
#pragma unroll
    for (int tl = 0; tl < 4; ++tl) {
      v4f g0 = {}, g1 = {};
#pragma unroll
      for (int c = 0; c < 4; ++c) {
        g0 = __builtin_amdgcn_mfma_f32_16x16x32_bf16(a5[0][c], bfr[tl * 4 + c], g0, 0, 0, 0);
        g1 = __builtin_amdgcn_mfma_f32_16x16x32_bf16(a5[1][c], bfr[tl * 4 + c], g1, 0, 0, 0);
      }
      float s2x = s2v[tl];
#pragma unroll
      for (int r = 0; r < 4; ++r) {
        dmin[0][r] = fminf(dmin[0][r], a2s[0][r] + s2x - 2.f * g0[r]);
        dmin[1][r] = fminf(dmin[1][r], a2s[1][r] + s2x - 2.f * g1[r]);
      }
    }
  }
  {
    v8s bfr[12];
#pragma unroll
    for (int tl = 0; tl < 3; ++tl)
#pragma unroll
      for (int c = 0; c < 4; ++c)
        bfr[tl * 4 + c] = sfrag(s_wt, (tl + 4) * 4 + c, lane);
#pragma unroll
    for (int tl = 0; tl < 3; ++tl) {
      v4f g0 = {}, g1 = {};
#pragma unroll
      for (int c = 0; c < 4; ++c) {
        g0 = __builtin_amdgcn_mfma_f32_16x16x32_bf16(a5[0][c], bfr[tl * 4 + c], g0, 0, 0, 0);
        g1 = __builtin_amdgcn_mfma_f32_16x16x32_bf16(a5[1][c], bfr[tl * 4 + c], g1, 0, 0, 0);
      }
      float s2x = s2v[tl + 4];
#pragma unroll
      for (int r = 0; r < 4; ++r) {
        dmin[0][r] = fminf(dmin[0][r], a2s[0][r] + s2x - 2.f * g0[r]);
        dmin[1][r] = fminf(dmin[1][r], a2s[1][r] + s2x - 2.f * g1[r]);
      }
    }
  }
#pragma unroll
  for (int tt = 0; tt < 2; ++tt)
#pragma unroll
    for (int r = 0; r < 4; ++r)
#pragma unroll
      for (int msk = 1; msk < 16; msk <<= 1)
        dmin[tt][r] = fminf(dmin[tt][r], __shfl_xor(dmin[tt][r], msk, 16));

  if (m == 0) {
#pragma unroll
    for (int tt = 0; tt < 2; ++tt)
#pragma unroll
      for (int r = 0; r < 4; ++r) {
        int rl = w * 32 + tt * 16 + q * 4 + r;
        float p = pe[tt][r] * (1.f / 128.f);
        float nov = fminf(1.f, sqrtf(fmaxf(dmin[tt][r], 0.f)) * 0.1f);
        s_o[0][rl] = p;
        s_o[1][rl] = nov;
        s_o[2][rl] = 0.5f * (p + nov);
      }
  }
  __syncthreads();
  const size_t base = (size_t)blockIdx.x * 128;
  for (int idx = tid; idx < 384; idx += 256) {
    int j = idx >> 7, r = idx & 127;
    out[(size_t)j * B_TOT + base + r] = s_o[j][r];
  }
}

extern "C" void kernel_launch(void* const* d_in, const int* in_sizes, int n_in,
                              void* d_out, int out_size, void* d_ws, size_t ws_size,
                              hipStream_t stream) {
  const float* state      = (const float*)d_in[0];
  const float* action     = (const float*)d_in[1];
  const float* next_state = (const float*)d_in[2];
  const float* seen       = (const float*)d_in[3];
  const float* W1         = (const float*)d_in[4];
  const float* b1         = (const float*)d_in[5];
  const float* W2         = (const float*)d_in[6];
  const float* b2         = (const float*)d_in[7];
  const float* Wf         = (const float*)d_in[8];
  const float* bf_        = (const float*)d_in[9];

  unsigned short* wsb = (unsigned short*)d_ws;
  float* s2 = (float*)((char*)d_ws + WS_S2_BYTES);

  curiosity_prep<<<292, 256, 0, stream>>>(W1, W2, Wf, seen, wsb, s2);
  curiosity_main<<<2048, 256, 0, stream>>>(state, action, next_state, b1, b2, bf_,
                                           wsb, s2, (float*)d_out);
}